// Round 1
// baseline (66.953 us; speedup 1.0000x reference)
//
#include <hip/hip_runtime.h>
#include <cmath>

#define NB  8
#define NTT 1024
#define MM  64
#define LL  16
#define EE  128

__global__ __launch_bounds__(256) void a2l_kernel(
    const float* __restrict__ agent,
    const float* __restrict__ lane,
    const float* __restrict__ W,
    const float* __restrict__ bias,
    float* __restrict__ out)
{
    __shared__ float s_edge[MM][13];   // +1 pad: conflict-free phase-1 writes
    const int bidx = blockIdx.x;       // b*1024 + nt
    const int b    = bidx >> 10;
    const int tid  = threadIdx.x;

    // ---- Phase 1: threads 0..63 compute edge[12] for lane-center m = tid ----
    if (tid < MM) {
        const int m = tid;
        const float4* ap = reinterpret_cast<const float4*>(agent + (size_t)bidx * 8);
        const float4 a0 = ap[0];
        const float4 a1 = ap[1];
        const float px = a0.x, py = a0.y, ps = a0.w, pc = a1.x;
        const bool z1 = (a0.x == 0.f) & (a0.y == 0.f) & (a0.z == 0.f) & (a0.w == 0.f) &
                        (a1.x == 0.f) & (a1.y == 0.f) & (a1.z == 0.f) & (a1.w == 0.f);
        const float f1 = z1 ? 0.f : 1.f;

        const float4* lp = reinterpret_cast<const float4*>(lane + ((size_t)b * MM + m) * 64);

        float best = INFINITY;
        float e0 = 0.f, e1 = 0.f, e2 = 0.f, e3 = 0.f;   // argmin point
        float c0 = 0.f, c1 = 0.f, c2 = 0.f, c3 = 0.f;   // l = 0
        float d0 = 0.f, d1 = 0.f, d2 = 0.f, d3 = 0.f;   // l = 15
#pragma unroll
        for (int l = 0; l < LL; ++l) {
            const float4 lv = lp[l];                    // lx, ly, ls, lc
            const bool z2 = (lv.x == 0.f) & (lv.y == 0.f) & (lv.z == 0.f) & (lv.w == 0.f);
            const float f = z2 ? 0.f : f1;
            const float dxw = px - lv.x;
            const float dyw = py - lv.y;
            const float v0 = (dxw * lv.w + dyw * lv.z) * 0.1f * f;  // delta_x/10
            const float v1 = (dyw * lv.w - dxw * lv.z) * 0.1f * f;  // delta_y/10
            const float v2 = (ps * lv.w - pc * lv.z) * f;           // ds
            const float v3 = (pc * lv.w + ps * lv.z) * f;           // dc
            const float ad = fabsf(v0);
            if (ad < best) { best = ad; e0 = v0; e1 = v1; e2 = v2; e3 = v3; } // first-min
            if (l == 0)      { c0 = v0; c1 = v1; c2 = v2; c3 = v3; }
            if (l == LL - 1) { d0 = v0; d1 = v1; d2 = v2; d3 = v3; }
        }
        float* se = s_edge[m];
        se[0] = e0;  se[1] = e1;  se[2]  = e2;  se[3]  = e3;
        se[4] = c0;  se[5] = c1;  se[6]  = c2;  se[7]  = c3;
        se[8] = d0;  se[9] = d1;  se[10] = d2;  se[11] = d3;
    }
    __syncthreads();

    // ---- Phase 2: each thread owns 4 consecutive channels, loops 8 m's ----
    const int e0i = (tid & 31) * 4;     // channel base 0..124
    const int mg  = tid >> 5;           // 0..7

    float w[4][12];
#pragma unroll
    for (int j = 0; j < 4; ++j) {
        const float4* wp = reinterpret_cast<const float4*>(W + (size_t)(e0i + j) * 12);
        const float4 w0 = wp[0], w1 = wp[1], w2 = wp[2];
        w[j][0] = w0.x; w[j][1]  = w0.y; w[j][2]  = w0.z; w[j][3]  = w0.w;
        w[j][4] = w1.x; w[j][5]  = w1.y; w[j][6]  = w1.z; w[j][7]  = w1.w;
        w[j][8] = w2.x; w[j][9]  = w2.y; w[j][10] = w2.z; w[j][11] = w2.w;
    }
    float4 bb;
    bb.x = bias[e0i + 0]; bb.y = bias[e0i + 1];
    bb.z = bias[e0i + 2]; bb.w = bias[e0i + 3];

    float* outp = out + (size_t)bidx * (MM * EE);
#pragma unroll
    for (int it = 0; it < 8; ++it) {
        const int m = it * 8 + mg;
        float acc0 = bb.x, acc1 = bb.y, acc2 = bb.z, acc3 = bb.w;
#pragma unroll
        for (int d = 0; d < 12; ++d) {
            const float ed = s_edge[m][d];      // wave-broadcast
            acc0 += ed * w[0][d];
            acc1 += ed * w[1][d];
            acc2 += ed * w[2][d];
            acc3 += ed * w[3][d];
        }
        float4 res = make_float4(acc0, acc1, acc2, acc3);
        *reinterpret_cast<float4*>(outp + (size_t)m * EE + e0i) = res;
    }
}

extern "C" void kernel_launch(void* const* d_in, const int* in_sizes, int n_in,
                              void* d_out, int out_size, void* d_ws, size_t ws_size,
                              hipStream_t stream) {
    const float* agent = (const float*)d_in[0];
    const float* lane  = (const float*)d_in[1];
    const float* W     = (const float*)d_in[2];
    const float* bias  = (const float*)d_in[3];
    float* out = (float*)d_out;

    dim3 grid(NB * NTT);
    dim3 block(256);
    a2l_kernel<<<grid, block, 0, stream>>>(agent, lane, W, bias, out);
}

// Round 3
// 63.952 us; speedup vs baseline: 1.0469x; 1.0469x over previous
//
#include <hip/hip_runtime.h>
#include <cmath>

#define NB   8
#define NTT  1024
#define MM   64
#define LL   16
#define EE   128
#define NTB  4          // (b,nt) positions per block

typedef float f32x4 __attribute__((ext_vector_type(4)));

__global__ __launch_bounds__(256) void a2l_kernel(
    const float* __restrict__ agent,
    const float* __restrict__ lane,
    const float* __restrict__ W,
    const float* __restrict__ bias,
    float* __restrict__ out)
{
    __shared__ f32x4 sE0[NTB][MM];   // argmin point  (4 floats)
    __shared__ f32x4 sE1[NTB][MM];   // l = 0 slice
    __shared__ f32x4 sE2[NTB][MM];   // l = 15 slice

    const int tid       = threadIdx.x;
    const int bidx_base = blockIdx.x * NTB;          // 4-aligned => same b for all 4
    const int b         = bidx_base >> 10;

    // ---- Phase 1: 256 threads = 4 nt × 64 m, one edge each ----
    {
        const int nt = tid >> 6;          // 0..3
        const int m  = tid & 63;          // 0..63
        const int bidx = bidx_base + nt;

        const f32x4* ap = reinterpret_cast<const f32x4*>(agent + (size_t)bidx * 8);
        const f32x4 a0 = ap[0];
        const f32x4 a1 = ap[1];
        const float px = a0.x, py = a0.y, ps = a0.w, pc = a1.x;
        const bool z1 = (a0.x == 0.f) & (a0.y == 0.f) & (a0.z == 0.f) & (a0.w == 0.f) &
                        (a1.x == 0.f) & (a1.y == 0.f) & (a1.z == 0.f) & (a1.w == 0.f);
        const float f1 = z1 ? 0.f : 1.f;

        const f32x4* lp = reinterpret_cast<const f32x4*>(lane + ((size_t)b * MM + m) * 64);

        float best = INFINITY;
        f32x4 eMin = (f32x4)(0.f);
        f32x4 eL0  = (f32x4)(0.f);
        f32x4 eL15 = (f32x4)(0.f);
#pragma unroll
        for (int l = 0; l < LL; ++l) {
            const f32x4 lv = lp[l];                   // lx, ly, ls, lc
            const bool z2 = (lv.x == 0.f) & (lv.y == 0.f) & (lv.z == 0.f) & (lv.w == 0.f);
            const float f = z2 ? 0.f : f1;
            const float dxw = px - lv.x;
            const float dyw = py - lv.y;
            f32x4 v;
            v.x = (dxw * lv.w + dyw * lv.z) * 0.1f * f;   // delta_x / 10
            v.y = (dyw * lv.w - dxw * lv.z) * 0.1f * f;   // delta_y / 10
            v.z = (ps * lv.w - pc * lv.z) * f;            // ds
            v.w = (pc * lv.w + ps * lv.z) * f;            // dc
            const float ad = fabsf(v.x);
            if (ad < best) { best = ad; eMin = v; }       // strict < keeps FIRST min
            if (l == 0)      eL0  = v;
            if (l == LL - 1) eL15 = v;
        }
        sE0[nt][m] = eMin;
        sE1[nt][m] = eL0;
        sE2[nt][m] = eL15;
    }
    __syncthreads();

    // ---- Phase 2: thread owns 4 consecutive channels; loops 4 nt × 8 m-groups ----
    const int e0i = (tid & 31) * 4;     // channel base 0..124
    const int mg  = tid >> 5;           // 0..7

    float w[4][12];
#pragma unroll
    for (int j = 0; j < 4; ++j) {
        const f32x4* wp = reinterpret_cast<const f32x4*>(W + (size_t)(e0i + j) * 12);
        const f32x4 w0 = wp[0], w1 = wp[1], w2 = wp[2];
        w[j][0] = w0.x; w[j][1]  = w0.y; w[j][2]  = w0.z; w[j][3]  = w0.w;
        w[j][4] = w1.x; w[j][5]  = w1.y; w[j][6]  = w1.z; w[j][7]  = w1.w;
        w[j][8] = w2.x; w[j][9]  = w2.y; w[j][10] = w2.z; w[j][11] = w2.w;
    }
    float bb0 = bias[e0i + 0], bb1 = bias[e0i + 1];
    float bb2 = bias[e0i + 2], bb3 = bias[e0i + 3];

#pragma unroll
    for (int nt = 0; nt < NTB; ++nt) {
        float* outp = out + (size_t)(bidx_base + nt) * (MM * EE);
#pragma unroll
        for (int it = 0; it < 8; ++it) {
            const int m = it * 8 + mg;
            const f32x4 p = sE0[nt][m];    // half-wave broadcast, conflict-free
            const f32x4 q = sE1[nt][m];
            const f32x4 r = sE2[nt][m];
            float acc0 = bb0, acc1 = bb1, acc2 = bb2, acc3 = bb3;
            acc0 += p.x*w[0][0] + p.y*w[0][1] + p.z*w[0][2]  + p.w*w[0][3]
                  + q.x*w[0][4] + q.y*w[0][5] + q.z*w[0][6]  + q.w*w[0][7]
                  + r.x*w[0][8] + r.y*w[0][9] + r.z*w[0][10] + r.w*w[0][11];
            acc1 += p.x*w[1][0] + p.y*w[1][1] + p.z*w[1][2]  + p.w*w[1][3]
                  + q.x*w[1][4] + q.y*w[1][5] + q.z*w[1][6]  + q.w*w[1][7]
                  + r.x*w[1][8] + r.y*w[1][9] + r.z*w[1][10] + r.w*w[1][11];
            acc2 += p.x*w[2][0] + p.y*w[2][1] + p.z*w[2][2]  + p.w*w[2][3]
                  + q.x*w[2][4] + q.y*w[2][5] + q.z*w[2][6]  + q.w*w[2][7]
                  + r.x*w[2][8] + r.y*w[2][9] + r.z*w[2][10] + r.w*w[2][11];
            acc3 += p.x*w[3][0] + p.y*w[3][1] + p.z*w[3][2]  + p.w*w[3][3]
                  + q.x*w[3][4] + q.y*w[3][5] + q.z*w[3][6]  + q.w*w[3][7]
                  + r.x*w[3][8] + r.y*w[3][9] + r.z*w[3][10] + r.w*w[3][11];
            f32x4 res;
            res.x = acc0; res.y = acc1; res.z = acc2; res.w = acc3;
            __builtin_nontemporal_store(res,
                reinterpret_cast<f32x4*>(outp + (size_t)m * EE + e0i));
        }
    }
}

extern "C" void kernel_launch(void* const* d_in, const int* in_sizes, int n_in,
                              void* d_out, int out_size, void* d_ws, size_t ws_size,
                              hipStream_t stream) {
    const float* agent = (const float*)d_in[0];
    const float* lane  = (const float*)d_in[1];
    const float* W     = (const float*)d_in[2];
    const float* bias  = (const float*)d_in[3];
    float* out = (float*)d_out;

    dim3 grid((NB * NTT) / NTB);   // 2048 blocks
    dim3 block(256);
    a2l_kernel<<<grid, block, 0, stream>>>(agent, lane, W, bias, out);
}